// Round 2
// 607.608 us; speedup vs baseline: 1.0430x; 1.0430x over previous
//
#include <hip/hip_runtime.h>

// GNNCASimple — fused per-node pipeline (bf16 MFMA, fp32 accum), fp32 I/O.
// Step s: xform: p = relu(h@W_pre+b_pre)   [LDS, buffer shared with m]
//                m = relu(p@W_conv+b_conv) [same LDS buffer, WAR barrier]
//                pw2 = p@Wp2 (fused), q = m@Wz
//         agg:   zq = segsum(q[src]); h' = bf16(zq+pw2+b_post)  (fp32 out at last step)
// r13 == r12 resubmit (round-1 bench died infra-side: "container failed twice",
// no compile/verify/profile output; audit found no OOB/LDS/alignment defect).
// r12: xform latency fixes —
//  (a) __launch_bounds__(256,3): r11's (256,4) capped regs at 128/wave; accm+accw
//      (80 AGPR) + 36 operand VGPRs exceeded it -> compiler could not pipeline the
//      per-ch Wct/Wp2t L2 loads (VGPR_Count=64, MfmaUtil 12%). Now explicit 2-deep
//      dbuf on all global B-fragments.
//  (b) coalesced epilogues: q and pw2 tiles staged in LDS (bf16) then stored as
//      block-contiguous uint4 (8KB/tile). r11's 2B/32B/64B partial-line stores gave
//      2.1x FETCH (RFO) and 2.1x WRITE amplification (28/81 MB vs 13/38 ideal).
//  (c) pw2 stored bf16 [NPAD][64]: halves its write + agg's read.

#define NN 100000
#define NPAD 100064
#define FS 64
#define HH 256
#define NE 1600000
#define NSTEPS 4
#define GA 128                    // fillA blocks
#define EPB (NE / GA)             // 12500 edges per fillA block
#define BK2SH 9                   // log2(nodes per coarse bucket)
#define BS2 (1 << BK2SH)          // 512
#define NBK2 ((NN + BS2 - 1) / BS2)   // 196 buckets

typedef unsigned short u16;
typedef unsigned int u32;
typedef __attribute__((ext_vector_type(8))) short bfrag;   // 8 bf16 = 4 VGPRs (MFMA A/B)
typedef __attribute__((ext_vector_type(4))) float ffrag;   // 4 fp32 (MFMA C/D)

static __device__ __forceinline__ u16 f2bf(float f) {  // RNE
    union { float f; u32 u; } v; v.f = f;
    return (u16)((v.u + 0x7fffu + ((v.u >> 16) & 1u)) >> 16);
}
static __device__ __forceinline__ float bf2f(u16 h) {
    union { u32 u; float f; } v; v.u = (u32)h << 16; return v.f;
}
static __device__ __forceinline__ u32 pack2bf(float a, float b) {
    return (u32)f2bf(a) | ((u32)f2bf(b) << 16);
}

// ---------------- x (fp32) -> hbf (bf16) ----------------
__global__ void cvt_x_k(const float4* __restrict__ x, uint2* __restrict__ hbf, int n4) {
    int i = blockIdx.x * 256 + threadIdx.x;
    if (i < n4) {
        float4 v = x[i];
        hbf[i] = make_uint2(pack2bf(v.x, v.y), pack2bf(v.z, v.w));
    }
}

// ---------------- all weight transposes (fp32 [K][C] -> bf16 [C][K]) in one launch ----------------
__global__ void prep_w_k(const float* __restrict__ W_pre, const float* __restrict__ W_conv,
                         const float* __restrict__ W_post,
                         u16* __restrict__ Wpt, u16* __restrict__ Wct,
                         u16* __restrict__ Wzt, u16* __restrict__ Wp2t) {
    int i = blockIdx.x * 256 + threadIdx.x;
    if (i < 65536) {                       // Wct [256][256] <- W_conv [256][256]
        int c = i >> 8, k = i & 255;
        Wct[i] = f2bf(W_conv[k * HH + c]);
    } else if (i < 81920) {                // Wpt [256][64] <- W_pre [64][256]
        int j = i - 65536;
        int c = j >> 6, k = j & 63;
        Wpt[j] = f2bf(W_pre[k * HH + c]);
    } else if (i < 98304) {                // Wzt [64][256] <- W_post rows [0,256)
        int j = i - 81920;
        int c = j >> 8, k = j & 255;
        Wzt[j] = f2bf(W_post[k * FS + c]);
    } else if (i < 114688) {               // Wp2t [64][256] <- W_post rows [256,512)
        int j = i - 98304;
        int c = j >> 8, k = j & 255;
        Wp2t[j] = f2bf(W_post[(HH + k) * FS + c]);
    }
}

// ---------------- fillA: group packed edges into per-block private segments by bucket ----------------
__global__ __launch_bounds__(256) void fillA_k(const int* __restrict__ dst, const int* __restrict__ src,
                                               int* __restrict__ cntM, int* __restrict__ offM,  // [NBK2][GA]
                                               u32* __restrict__ tmp) {
    __shared__ int cnt[256];
    __shared__ int sc[256];
    __shared__ int cur[256];
    const int t = threadIdx.x, b = blockIdx.x;
    const int e0 = b * EPB;
    cnt[t] = 0;
    __syncthreads();
    for (int i = t; i < EPB; i += 256) atomicAdd(&cnt[dst[e0 + i] >> BK2SH], 1);
    __syncthreads();
    int v = cnt[t];
    sc[t] = v;
    __syncthreads();
    for (int o = 1; o < 256; o <<= 1) {
        int y = (t >= o) ? sc[t - o] : 0;
        __syncthreads();
        sc[t] += y;
        __syncthreads();
    }
    int excl = sc[t] - v;
    cur[t] = excl;
    if (t < NBK2) {
        cntM[t * GA + b] = v;
        offM[t * GA + b] = excl;
    }
    __syncthreads();
    u32* seg = tmp + (size_t)b * EPB;
    for (int i = t; i < EPB; i += 256) {
        int d = dst[e0 + i], s = src[e0 + i];
        int pos = atomicAdd(&cur[d >> BK2SH], 1);
        seg[pos] = ((u32)(d & (BS2 - 1)) << 23) | (u32)s;   // 9b local node | 23b src
    }
}

// ---------------- bscan: bucket totals from cntM + exclusive scan -> bstart ----------------
__global__ void bscan_k(const int* __restrict__ cntM, int* __restrict__ bstart) {
    __shared__ int sh[256];
    const int t = threadIdx.x;
    int tot = 0;
    if (t < NBK2)
        for (int b = 0; b < GA; b++) tot += cntM[t * GA + b];
    sh[t] = tot;
    __syncthreads();
    for (int o = 1; o < 256; o <<= 1) {
        int y = (t >= o) ? sh[t - o] : 0;
        __syncthreads();
        sh[t] += y;
        __syncthreads();
    }
    if (t < NBK2) bstart[t] = sh[t] - tot;
    if (t == 255) bstart[NBK2] = sh[255];  // == NE
}

// ---------------- fillB: one block per bucket; computes offsets AND scatters srcs ----------------
__global__ __launch_bounds__(256) void fillB_k(const u32* __restrict__ tmp,
                                               const int* __restrict__ cntM, const int* __restrict__ offM,
                                               const int* __restrict__ bstart,
                                               int* __restrict__ offsets, int* __restrict__ srcs) {
    __shared__ int cnt[BS2];
    __shared__ int cur[BS2];
    __shared__ int runlen[GA];
    __shared__ int runoff[GA];
    const int t = threadIdx.x, k = blockIdx.x;
    const int nodeBase = k << BK2SH;
    cnt[t] = 0;
    cnt[t + 256] = 0;
    if (t < GA) {
        runlen[t] = cntM[k * GA + t];
        runoff[t] = offM[k * GA + t];
    }
    __syncthreads();
    const int rsub = t >> 6;
    const int elane = t & 63;
    // pass 1: per-node counts
    for (int g = 0; g < GA / 4; g++) {
        int rb = g * 4 + rsub;
        int len = runlen[rb];
        const u32* run = tmp + (size_t)rb * EPB + runoff[rb];
        for (int e = elane; e < len; e += 64) atomicAdd(&cnt[run[e] >> 23], 1);
    }
    __syncthreads();
    // scan 512 counters with 256 threads (sequential pairs + Hillis-Steele on pair sums)
    int a = cnt[2 * t], b2 = cnt[2 * t + 1];
    int s = a + b2;
    cur[t] = s;
    __syncthreads();
    for (int o = 1; o < 256; o <<= 1) {
        int y = (t >= o) ? cur[t - o] : 0;
        __syncthreads();
        cur[t] += y;
        __syncthreads();
    }
    int exclPair = cur[t] - s;
    __syncthreads();   // everyone done reading cur as scan array
    const int base = bstart[k];
    int o0 = base + exclPair;
    int o1 = o0 + a;
    int n0 = nodeBase + 2 * t, n1 = n0 + 1;
    if (n0 < NN) offsets[n0] = o0;
    if (n1 < NN) offsets[n1] = o1;
    cur[2 * t] = o0;
    cur[2 * t + 1] = o1;
    __syncthreads();
    // pass 2: scatter src into contiguous window (cache-hot)
    for (int g = 0; g < GA / 4; g++) {
        int rb = g * 4 + rsub;
        int len = runlen[rb];
        const u32* run = tmp + (size_t)rb * EPB + runoff[rb];
        for (int e = elane; e < len; e += 64) {
            u32 p = run[e];
            int pos = atomicAdd(&cur[p >> 23], 1);
            srcs[pos] = (int)(p & 0x7FFFFFu);
        }
    }
}

__global__ void final_off_k(int* __restrict__ offsets) {
    if (threadIdx.x == 0) offsets[NN] = NE;
}

// ---------------- fused node transform (r12: dbuf'd operands + coalesced epilogues) ----------------
__global__ __launch_bounds__(256, 3) void xform_k(const u16* __restrict__ hbf,     // [NPAD][64]
                                                  const u16* __restrict__ Wpt,     // [256][64]
                                                  const float* __restrict__ b_pre,
                                                  const u16* __restrict__ Wct,     // [256][256]
                                                  const float* __restrict__ b_conv,
                                                  const u16* __restrict__ Wzt,     // [64][256]
                                                  const u16* __restrict__ Wp2t,    // [64][256]
                                                  u16* __restrict__ qbf,           // [NPAD][64] bf16
                                                  u16* __restrict__ pw2o) {        // [NPAD][64] bf16
    __shared__ __align__(16) u16 ts[64 * 264];   // p tile, then m tile (bf16, stride 264)
    __shared__ __align__(16) u16 stA[64 * 72];   // pw2 staging (stride 72 breaks bank aliasing)
    __shared__ __align__(16) u16 stB[64 * 72];   // q staging
    const int t = threadIdx.x;
    const int wave = t >> 6, lane = t & 63;
    const int quad = lane >> 4, l16 = lane & 15;
    const int nodeBase = blockIdx.x * 64;

    // ---- stage 1: p = relu(h @ W_pre + b_pre) -> ts ----
    {
        ffrag acc[4][4];
#pragma unroll
        for (int mt = 0; mt < 4; mt++)
#pragma unroll
            for (int nt = 0; nt < 4; nt++) acc[mt][nt] = (ffrag)0.f;
#pragma unroll
        for (int ch = 0; ch < 2; ch++) {
            const int kb = ch * 32 + quad * 8;
            bfrag a[4], b[4];
#pragma unroll
            for (int mt = 0; mt < 4; mt++)
                a[mt] = *(const bfrag*)(hbf + (size_t)(nodeBase + mt * 16 + l16) * FS + kb);
#pragma unroll
            for (int nt = 0; nt < 4; nt++)
                b[nt] = *(const bfrag*)(Wpt + (size_t)(wave * 64 + nt * 16 + l16) * FS + kb);
#pragma unroll
            for (int mt = 0; mt < 4; mt++)
#pragma unroll
                for (int nt = 0; nt < 4; nt++)
                    acc[mt][nt] = __builtin_amdgcn_mfma_f32_16x16x32_bf16(a[mt], b[nt], acc[mt][nt], 0, 0, 0);
        }
#pragma unroll
        for (int nt = 0; nt < 4; nt++) {
            const int col = wave * 64 + nt * 16 + l16;
            const float bv = b_pre[col];
#pragma unroll
            for (int mt = 0; mt < 4; mt++)
#pragma unroll
                for (int r = 0; r < 4; r++)
                    ts[(mt * 16 + quad * 4 + r) * 264 + col] = f2bf(fmaxf(acc[mt][nt][r] + bv, 0.f));
        }
    }
    __syncthreads();   // #1: p visible

    // ---- stage 2: m = relu(p @ W_conv + b_conv) [regs], pw2 = p @ Wp2 (fused) ----
    // Global B-fragments double-buffered so L2 latency hides under the MFMA cluster.
    ffrag accm[4][4];
    ffrag accw[4];
    {
#pragma unroll
        for (int mt = 0; mt < 4; mt++) {
            accw[mt] = (ffrag)0.f;
#pragma unroll
            for (int nt = 0; nt < 4; nt++) accm[mt][nt] = (ffrag)0.f;
        }
        bfrag b[2][4], bw[2];
        {
            const int kb0 = quad * 8;
#pragma unroll
            for (int nt = 0; nt < 4; nt++)
                b[0][nt] = *(const bfrag*)(Wct + (size_t)(wave * 64 + nt * 16 + l16) * HH + kb0);
            bw[0] = *(const bfrag*)(Wp2t + (size_t)(wave * 16 + l16) * HH + kb0);
        }
#pragma unroll
        for (int ch = 0; ch < 8; ch++) {
            const int cur = ch & 1, nxt = cur ^ 1;
            if (ch < 7) {
                const int kb2 = (ch + 1) * 32 + quad * 8;
#pragma unroll
                for (int nt = 0; nt < 4; nt++)
                    b[nxt][nt] = *(const bfrag*)(Wct + (size_t)(wave * 64 + nt * 16 + l16) * HH + kb2);
                bw[nxt] = *(const bfrag*)(Wp2t + (size_t)(wave * 16 + l16) * HH + kb2);
            }
            const int kb = ch * 32 + quad * 8;
            bfrag a[4];
#pragma unroll
            for (int mt = 0; mt < 4; mt++)
                a[mt] = *(const bfrag*)(ts + (mt * 16 + l16) * 264 + kb);
#pragma unroll
            for (int mt = 0; mt < 4; mt++) {
#pragma unroll
                for (int nt = 0; nt < 4; nt++)
                    accm[mt][nt] = __builtin_amdgcn_mfma_f32_16x16x32_bf16(a[mt], b[cur][nt], accm[mt][nt], 0, 0, 0);
                accw[mt] = __builtin_amdgcn_mfma_f32_16x16x32_bf16(a[mt], bw[cur], accw[mt], 0, 0, 0);
            }
        }
    }
    __syncthreads();   // #2: all p reads done (WAR before m overwrites ts)

    // ---- write m -> ts, pw2 -> stA (bf16) ----
    {
#pragma unroll
        for (int nt = 0; nt < 4; nt++) {
            const int col = wave * 64 + nt * 16 + l16;
            const float bv = b_conv[col];
#pragma unroll
            for (int mt = 0; mt < 4; mt++)
#pragma unroll
                for (int r = 0; r < 4; r++)
                    ts[(mt * 16 + quad * 4 + r) * 264 + col] = f2bf(fmaxf(accm[mt][nt][r] + bv, 0.f));
        }
        const int colw = wave * 16 + l16;
#pragma unroll
        for (int mt = 0; mt < 4; mt++)
#pragma unroll
            for (int r = 0; r < 4; r++)
                stA[(mt * 16 + quad * 4 + r) * 72 + colw] = f2bf(accw[mt][r]);
    }
    __syncthreads();   // #3: m and stA visible

    // ---- coalesced pw2 store: block tile is 64 rows x 128B, fully contiguous ----
#pragma unroll
    for (int s = 0; s < 2; s++) {
        const int j = t + s * 256;           // 512 tasks: row = j>>3, 16B seg = j&7
        const int row = j >> 3, seg = j & 7;
        uint4 v = *(const uint4*)(stA + row * 72 + seg * 8);
        *(uint4*)(pw2o + (size_t)(nodeBase + row) * FS + seg * 8) = v;
    }

    // ---- stage 3: q = m @ Wz (bz double-buffered) ----
    {
        ffrag qa[4];
#pragma unroll
        for (int mt = 0; mt < 4; mt++) qa[mt] = (ffrag)0.f;
        bfrag bz[2];
        bz[0] = *(const bfrag*)(Wzt + (size_t)(wave * 16 + l16) * HH + quad * 8);
#pragma unroll
        for (int ch = 0; ch < 8; ch++) {
            const int cur = ch & 1;
            if (ch < 7)
                bz[cur ^ 1] = *(const bfrag*)(Wzt + (size_t)(wave * 16 + l16) * HH + (ch + 1) * 32 + quad * 8);
            const int kb = ch * 32 + quad * 8;
#pragma unroll
            for (int mt = 0; mt < 4; mt++) {
                bfrag am = *(const bfrag*)(ts + (mt * 16 + l16) * 264 + kb);
                qa[mt] = __builtin_amdgcn_mfma_f32_16x16x32_bf16(am, bz[cur], qa[mt], 0, 0, 0);
            }
        }
        const int col = wave * 16 + l16;
#pragma unroll
        for (int mt = 0; mt < 4; mt++)
#pragma unroll
            for (int r = 0; r < 4; r++)
                stB[(mt * 16 + quad * 4 + r) * 72 + col] = f2bf(qa[mt][r]);
    }
    __syncthreads();   // #4: stB visible

    // ---- coalesced q store ----
#pragma unroll
    for (int s = 0; s < 2; s++) {
        const int j = t + s * 256;
        const int row = j >> 3, seg = j & 7;
        uint4 v = *(const uint4*)(stB + row * 72 + seg * 8);
        *(uint4*)(qbf + (size_t)(nodeBase + row) * FS + seg * 8) = v;
    }
}

// ---------------- aggregation + h-build (pw2 now packed bf16 pairs) ----------------
__global__ __launch_bounds__(256) void agg_k(const u32* __restrict__ q2,  // [NPAD][32] packed bf16 pairs
                                             const int* __restrict__ offsets,
                                             const int* __restrict__ srcs,
                                             const u32* __restrict__ pw2, // [NPAD][32] packed bf16 pairs
                                             const float* __restrict__ b_post,
                                             u32* __restrict__ hbf_out,   // [NPAD][32] packed (steps 0..2)
                                             float* __restrict__ outf) {  // [NN][64] (last step)
    const int wave = threadIdx.x >> 6;
    const int lane = threadIdx.x & 63;
    const int node = blockIdx.x * 4 + wave;
    const int half = lane >> 5, c = lane & 31;
    const int beg = offsets[node], end = offsets[node + 1];
    float ax = 0.f, ay = 0.f, bx = 0.f, by = 0.f;
    int e = beg + half;
    for (; e + 6 < end; e += 8) {
        int s0 = srcs[e], s1 = srcs[e + 2], s2 = srcs[e + 4], s3 = srcs[e + 6];
        u32 g0 = q2[(size_t)s0 * 32 + c];
        u32 g1 = q2[(size_t)s1 * 32 + c];
        u32 g2 = q2[(size_t)s2 * 32 + c];
        u32 g3 = q2[(size_t)s3 * 32 + c];
        ax += bf2f((u16)g0) + bf2f((u16)g1);
        ay += bf2f((u16)(g0 >> 16)) + bf2f((u16)(g1 >> 16));
        bx += bf2f((u16)g2) + bf2f((u16)g3);
        by += bf2f((u16)(g2 >> 16)) + bf2f((u16)(g3 >> 16));
    }
    for (; e < end; e += 2) {
        u32 g = q2[(size_t)srcs[e] * 32 + c];
        ax += bf2f((u16)g);
        ay += bf2f((u16)(g >> 16));
    }
    ax += bx; ay += by;
    ax += __shfl_xor(ax, 32);
    ay += __shfl_xor(ay, 32);
    if (half == 0) {
        u32 wp = pw2[(size_t)node * 32 + c];
        float2 b = *(const float2*)&b_post[2 * c];
        float hx = ax + bf2f((u16)wp) + b.x;
        float hy = ay + bf2f((u16)(wp >> 16)) + b.y;
        if (outf) {
            *(float2*)&outf[(size_t)node * FS + 2 * c] = make_float2(hx, hy);
        } else {
            hbf_out[(size_t)node * 32 + c] = pack2bf(hx, hy);
        }
    }
}

extern "C" void kernel_launch(void* const* d_in, const int* in_sizes, int n_in,
                              void* d_out, int out_size, void* d_ws, size_t ws_size,
                              hipStream_t stream) {
    const float* x      = (const float*)d_in[0];
    const int*   ei     = (const int*)d_in[1];
    const float* W_pre  = (const float*)d_in[2];
    const float* b_pre  = (const float*)d_in[3];
    const float* W_conv = (const float*)d_in[4];
    const float* b_conv = (const float*)d_in[5];
    const float* W_post = (const float*)d_in[6];
    const float* b_post = (const float*)d_in[7];
    float* out = (float*)d_out;

    char* ws = (char*)d_ws;
    size_t off = 0;
    auto alloc = [&](size_t bytes) -> char* {
        char* r = ws + off;
        off += (bytes + 255) & ~(size_t)255;
        return r;
    };
    u16* hbf     = (u16*)alloc((size_t)NPAD * FS * 2);    // 12.8 MB
    u16* qbf     = (u16*)alloc((size_t)NPAD * FS * 2);    // 12.8 MB
    u16* pw2     = (u16*)alloc((size_t)NPAD * FS * 2);    // 12.8 MB (bf16, was fp32)
    u32* tmp     = (u32*)alloc((size_t)NE * 4);           //  6.4 MB
    int* offsets = (int*)alloc((size_t)(NN + 1) * 4);
    int* srcs    = (int*)alloc((size_t)NE * 4);           //  6.4 MB
    int* cntM    = (int*)alloc((size_t)NBK2 * GA * 4);    // 100 KB
    int* offM    = (int*)alloc((size_t)NBK2 * GA * 4);    // 100 KB
    int* bstart  = (int*)alloc((size_t)(NBK2 + 1) * 4);
    u16* Wpt     = (u16*)alloc((size_t)HH * FS * 2);      // [256][64]
    u16* Wct     = (u16*)alloc((size_t)HH * HH * 2);      // [256][256]
    u16* Wzt     = (u16*)alloc((size_t)FS * HH * 2);      // [64][256]
    u16* Wp2t    = (u16*)alloc((size_t)FS * HH * 2);      // [64][256]
    (void)ws_size; (void)in_sizes; (void)n_in; (void)out_size;

    const int* dst = ei;       // edge_index[0] = aggregation targets
    const int* src = ei + NE;  // edge_index[1] = message sources

    // input cast / weight transposes
    cvt_x_k<<<(NN * FS / 4 + 255) / 256, 256, 0, stream>>>((const float4*)x, (uint2*)hbf, NN * FS / 4);
    prep_w_k<<<448, 256, 0, stream>>>(W_pre, W_conv, W_post, Wpt, Wct, Wzt, Wp2t);

    // CSR build (fillA buckets -> bucket scan -> fillB offsets+scatter)
    fillA_k<<<GA, 256, 0, stream>>>(dst, src, cntM, offM, tmp);
    bscan_k<<<1, 256, 0, stream>>>(cntM, bstart);
    fillB_k<<<NBK2, 256, 0, stream>>>(tmp, cntM, offM, bstart, offsets, srcs);
    final_off_k<<<1, 64, 0, stream>>>(offsets);

    const int GB = (NN + 63) / 64;  // 1563
    for (int s = 0; s < NSTEPS; s++) {
        xform_k<<<GB, 256, 0, stream>>>(hbf, Wpt, b_pre, Wct, b_conv, Wzt, Wp2t, qbf, pw2);
        if (s < NSTEPS - 1)
            agg_k<<<NN / 4, 256, 0, stream>>>((const u32*)qbf, offsets, srcs, (const u32*)pw2, b_post,
                                              (u32*)hbf, nullptr);
        else
            agg_k<<<NN / 4, 256, 0, stream>>>((const u32*)qbf, offsets, srcs, (const u32*)pw2, b_post,
                                              nullptr, out);
    }
}